// Round 4
// baseline (35475.320 us; speedup 1.0000x reference)
//
#include <hip/hip_runtime.h>
#include <hip/hip_fp16.h>

#define NTRAJ   256
#define NTP     512
#define NSTEPS  511
#define LATENT  256
#define INPUT   128
#define DEC_OUT 128

#define OUT_VOL ((size_t)NTRAJ * LATENT)                              // 65536
#define OUT_DTS (OUT_VOL + (size_t)NTRAJ * NSTEPS * DEC_OUT)          // 16809984

// Pair-interleaved fp16 weights (uint32 = half2 over adjacent K), [kp][C] layout.
#define WU_UG1  0
#define WU_UG2  49152
#define WU_UGT1 81920
#define WU_UGT2 131072
#define WU_RG1  163840
#define WU_RG2  212992
#define WU_NS1  245760
#define WU_NS2  294912
#define WU_DK1  327680
#define WU_DEC  360448
#define WU_TOT  376832

// d_ws byte layout
#define WS_CTR  (WU_TOT * 4)              // 1507328 : 64 groups x 5 counters, 64B stride
#define WS_EX   (WS_CTR + 64 * 5 * 64)    // exchange region
#define GRP_STRIDE 18944
#define GO_DKP  0                          // [4 slices][4 traj] f32 = 64 B
#define GO_G1H  64                         // [12][128] uint = 6144 B
#define GO_R    6208                       // [4][128] uint = 2048 B
#define GO_NS   8256                       // [4][128] uint = 2048 B
#define GO_Y    10304                      // [4][256] f32 = 4096 B
#define GO_YT   14400                      // [4][256] f32 = 4096 B

typedef _Float16 h2_t __attribute__((ext_vector_type(2)));
union U32H2 { unsigned int u; h2_t h; };

__device__ __forceinline__ float dot2f(unsigned int wu, unsigned int xu, float acc) {
    U32H2 a, b; a.u = wu; b.u = xu;
    return __builtin_amdgcn_fdot2(a.h, b.h, acc, false);
}
__device__ __forceinline__ unsigned pack2(float a, float b) {
    U32H2 r; r.h.x = (_Float16)a; r.h.y = (_Float16)b; return r.u;
}
__device__ __forceinline__ float wred(float v) {
    #pragma unroll
    for (int off = 32; off; off >>= 1) v += __shfl_down(v, off, 64);
    return v;
}
__device__ __forceinline__ float fast_sigmoid(float x) { return 1.0f / (1.0f + __expf(-x)); }
__device__ __forceinline__ float fast_tanh(float x) {
    float e = __expf(2.0f * x);
    return 1.0f - 2.0f / (e + 1.0f);
}
// pack (v_lane_even, v_lane_odd) into half2; valid in even lanes. Full-wave only.
__device__ __forceinline__ unsigned packpair(float v) {
    float vn = __shfl_xor(v, 1, 64);
    U32H2 r; r.h.x = (_Float16)v; r.h.y = (_Float16)vn; return r.u;
}

// group barrier: all 4 blocks of the group bump + wait (monotone counter)
__device__ __forceinline__ void gsync(unsigned int* ctr, unsigned int target) {
    __syncthreads();   // drains all waves' stores (vmcnt(0) before s_barrier)
    if (threadIdx.x == 0) {
        __hip_atomic_fetch_add(ctr, 1u, __ATOMIC_RELEASE, __HIP_MEMORY_SCOPE_AGENT);
        while (__hip_atomic_load(ctr, __ATOMIC_ACQUIRE, __HIP_MEMORY_SCOPE_AGENT) < target)
            __builtin_amdgcn_s_sleep(1);
    }
    __syncthreads();
}

// GEMV slice, C=256 matrix: 8 waves k-split, R kp-rows/wave, 4 traj x 4 cols/lane.
// part layout per traj: part[tr*512 + w*64 + col]
template<int R>
__device__ __forceinline__ void gemv256(const unsigned* __restrict__ Wp,
        const unsigned* __restrict__ x0, const unsigned* __restrict__ x1,
        const unsigned* __restrict__ x2, const unsigned* __restrict__ x3,
        float* __restrict__ part, const int w, const int lane, const int sl)
{
    const int r4 = lane >> 4;
    const int cl = (lane & 15) << 2;
    const int kp0 = w * R + r4;
    const unsigned* wp = Wp + (size_t)kp0 * 256 + (sl << 6) + cl;
    float a[4][4];
    #pragma unroll
    for (int t = 0; t < 4; ++t) { a[t][0] = 0.f; a[t][1] = 0.f; a[t][2] = 0.f; a[t][3] = 0.f; }
    #pragma unroll
    for (int i = 0; i < R / 4; ++i) {
        const uint4 wv = *(const uint4*)(wp + (size_t)(i << 2) * 256);
        const int k = kp0 + (i << 2);
        const unsigned xa = x0[k], xb = x1[k], xc = x2[k], xd = x3[k];
        a[0][0] = dot2f(wv.x, xa, a[0][0]); a[0][1] = dot2f(wv.y, xa, a[0][1]);
        a[0][2] = dot2f(wv.z, xa, a[0][2]); a[0][3] = dot2f(wv.w, xa, a[0][3]);
        a[1][0] = dot2f(wv.x, xb, a[1][0]); a[1][1] = dot2f(wv.y, xb, a[1][1]);
        a[1][2] = dot2f(wv.z, xb, a[1][2]); a[1][3] = dot2f(wv.w, xb, a[1][3]);
        a[2][0] = dot2f(wv.x, xc, a[2][0]); a[2][1] = dot2f(wv.y, xc, a[2][1]);
        a[2][2] = dot2f(wv.z, xc, a[2][2]); a[2][3] = dot2f(wv.w, xc, a[2][3]);
        a[3][0] = dot2f(wv.x, xd, a[3][0]); a[3][1] = dot2f(wv.y, xd, a[3][1]);
        a[3][2] = dot2f(wv.z, xd, a[3][2]); a[3][3] = dot2f(wv.w, xd, a[3][3]);
    }
    #pragma unroll
    for (int t = 0; t < 4; ++t) {
        #pragma unroll
        for (int j = 0; j < 4; ++j) {
            a[t][j] += __shfl_xor(a[t][j], 16, 64);
            a[t][j] += __shfl_xor(a[t][j], 32, 64);
        }
    }
    if (r4 == 0) {
        #pragma unroll
        for (int t = 0; t < 4; ++t)
            *(float4*)(part + t * 512 + (w << 6) + cl) =
                make_float4(a[t][0], a[t][1], a[t][2], a[t][3]);
    }
}

// GEMV slice, C=128 (dec): 128 kp-rows, 16/wave. part[tr*256 + w*32 + col]
__device__ __forceinline__ void gemv128d(const unsigned* __restrict__ Wp,
        const unsigned* __restrict__ x0, const unsigned* __restrict__ x1,
        const unsigned* __restrict__ x2, const unsigned* __restrict__ x3,
        float* __restrict__ part, const int w, const int lane, const int sl)
{
    const int r8 = lane >> 3;
    const int cl = (lane & 7) << 2;
    const int kp0 = (w << 4) + r8;
    const unsigned* wp = Wp + (size_t)kp0 * 128 + (sl << 5) + cl;
    float a[4][4];
    #pragma unroll
    for (int t = 0; t < 4; ++t) { a[t][0] = 0.f; a[t][1] = 0.f; a[t][2] = 0.f; a[t][3] = 0.f; }
    #pragma unroll
    for (int i = 0; i < 2; ++i) {
        const uint4 wv = *(const uint4*)(wp + (size_t)(i << 3) * 128);
        const int k = kp0 + (i << 3);
        const unsigned xa = x0[k], xb = x1[k], xc = x2[k], xd = x3[k];
        a[0][0] = dot2f(wv.x, xa, a[0][0]); a[0][1] = dot2f(wv.y, xa, a[0][1]);
        a[0][2] = dot2f(wv.z, xa, a[0][2]); a[0][3] = dot2f(wv.w, xa, a[0][3]);
        a[1][0] = dot2f(wv.x, xb, a[1][0]); a[1][1] = dot2f(wv.y, xb, a[1][1]);
        a[1][2] = dot2f(wv.z, xb, a[1][2]); a[1][3] = dot2f(wv.w, xb, a[1][3]);
        a[2][0] = dot2f(wv.x, xc, a[2][0]); a[2][1] = dot2f(wv.y, xc, a[2][1]);
        a[2][2] = dot2f(wv.z, xc, a[2][2]); a[2][3] = dot2f(wv.w, xc, a[2][3]);
        a[3][0] = dot2f(wv.x, xd, a[3][0]); a[3][1] = dot2f(wv.y, xd, a[3][1]);
        a[3][2] = dot2f(wv.z, xd, a[3][2]); a[3][3] = dot2f(wv.w, xd, a[3][3]);
    }
    #pragma unroll
    for (int t = 0; t < 4; ++t) {
        #pragma unroll
        for (int j = 0; j < 4; ++j) {
            a[t][j] += __shfl_xor(a[t][j], 8, 64);
            a[t][j] += __shfl_xor(a[t][j], 16, 64);
            a[t][j] += __shfl_xor(a[t][j], 32, 64);
        }
    }
    if (r8 == 0) {
        #pragma unroll
        for (int t = 0; t < 4; ++t)
            *(float4*)(part + t * 256 + (w << 5) + cl) =
                make_float4(a[t][0], a[t][1], a[t][2], a[t][3]);
    }
}

// ---- weight prep: fp32 -> k-pair-interleaved half2 (identical to R3) ----
extern "C" __global__ void __launch_bounds__(256)
convert_w(const float* __restrict__ ug_w1, const float* __restrict__ ug_w2,
          const float* __restrict__ ugt_w1, const float* __restrict__ ugt_w2,
          const float* __restrict__ rg_w1, const float* __restrict__ rg_w2,
          const float* __restrict__ ns_w1, const float* __restrict__ ns_w2,
          const float* __restrict__ dk_w1, const float* __restrict__ dec_w,
          unsigned int* __restrict__ ws)
{
    const int i = blockIdx.x * 256 + threadIdx.x;
    const float* s; int o; int cbits;
    if      (i < WU_UG2)  { s = ug_w1;  o = i;           cbits = 8; }
    else if (i < WU_UGT1) { s = ug_w2;  o = i - WU_UG2;  cbits = 8; }
    else if (i < WU_UGT2) { s = ugt_w1; o = i - WU_UGT1; cbits = 8; }
    else if (i < WU_RG1)  { s = ugt_w2; o = i - WU_UGT2; cbits = 8; }
    else if (i < WU_RG2)  { s = rg_w1;  o = i - WU_RG1;  cbits = 8; }
    else if (i < WU_NS1)  { s = rg_w2;  o = i - WU_RG2;  cbits = 8; }
    else if (i < WU_NS2)  { s = ns_w1;  o = i - WU_NS1;  cbits = 8; }
    else if (i < WU_DK1)  { s = ns_w2;  o = i - WU_NS2;  cbits = 8; }
    else if (i < WU_DEC)  { s = dk_w1;  o = i - WU_DK1;  cbits = 8; }
    else                  { s = dec_w;  o = i - WU_DEC;  cbits = 7; }
    const int C  = 1 << cbits;
    const int kp = o >> cbits;
    const int c  = o & (C - 1);
    const unsigned h0 = __half_as_ushort(__float2half(s[(2 * kp) * C + c]));
    const unsigned h1 = __half_as_ushort(__float2half(s[(2 * kp + 1) * C + c]));
    ws[i] = h0 | (h1 << 16);
}

extern "C" __global__ void __launch_bounds__(512)
init_ctrs(unsigned int* __restrict__ c) {
    for (int i = threadIdx.x; i < 5120; i += 512) c[i] = 0;
}

extern "C" __global__ void __launch_bounds__(512, 4)
rnn_decay_kernel4(const float* __restrict__ data, const float* __restrict__ ts,
                  const float* __restrict__ ug_b1, const float* __restrict__ ug_b2,
                  const float* __restrict__ ugt_b1, const float* __restrict__ ugt_b2,
                  const float* __restrict__ rg_b1, const float* __restrict__ rg_b2,
                  const float* __restrict__ ns_b1, const float* __restrict__ ns_b2,
                  const float* __restrict__ dk_b1, const float* __restrict__ dk_w2,
                  const float* __restrict__ dk_b2, const float* __restrict__ dec_b,
                  char* __restrict__ wsb, float* __restrict__ out)
{
    __shared__ __align__(16) float s_part[6144];     // [3 mats][4 tr][8 w][64]
    __shared__ __align__(16) float s_partd[1024];    // dec [4 tr][8 w][32]
    __shared__ __align__(16) unsigned s_in_h[768];   // [4][192]: ydec|xh pairs
    __shared__ __align__(16) unsigned s_ns_h[768];   // [4][192]: ydec*r|xh pairs
    __shared__ __align__(16) unsigned s_y_h[512];    // [4][128] y pairs (dk src)
    __shared__ __align__(16) unsigned s_v_h[512];    // [4][128] vol pairs
    __shared__ __align__(16) unsigned s_g1h[1536];   // [12][128] gate-h pairs
    __shared__ __align__(16) unsigned s_nsh[512];    // [4][128] ns-h pairs
    __shared__ __align__(16) float s_yf[1024];       // [4][256] y fp32
    __shared__ __align__(16) float s_ytf[1024];      // [4][256] yt fp32
    __shared__ __align__(16) float s_ydecf[1024];    // [4][256] ydec fp32
    __shared__ float s_u[256], s_ut[256];            // [4][64] col-slice
    __shared__ float s_mask[4];

    const int tid  = threadIdx.x;
    const int w    = tid >> 6;
    const int lane = tid & 63;
    const int bid  = blockIdx.x;
    const int sl   = bid >> 6;      // column slice 0..3
    const int g    = bid & 63;      // group 0..63

    const unsigned* Wts = (const unsigned*)wsb;
    const unsigned* UG1 = Wts + WU_UG1;  const unsigned* UG2  = Wts + WU_UG2;
    const unsigned* UGT1= Wts + WU_UGT1; const unsigned* UGT2 = Wts + WU_UGT2;
    const unsigned* RG1 = Wts + WU_RG1;  const unsigned* RG2  = Wts + WU_RG2;
    const unsigned* NS1 = Wts + WU_NS1;  const unsigned* NS2  = Wts + WU_NS2;
    const unsigned* DK1 = Wts + WU_DK1;  const unsigned* DECW = Wts + WU_DEC;

    unsigned int* ctrs = (unsigned int*)(wsb + WS_CTR) + (size_t)g * 5 * 16;
    char* exg = wsb + WS_EX + (size_t)g * GRP_STRIDE;
    float*    dkp_g = (float*)(exg + GO_DKP);
    unsigned* g1h_g = (unsigned*)(exg + GO_G1H);
    unsigned* rbuf_g = (unsigned*)(exg + GO_R);
    unsigned* nsb_g  = (unsigned*)(exg + GO_NS);
    float*    ybuf_g = (float*)(exg + GO_Y);
    float*    ytb_g  = (float*)(exg + GO_YT);

    // dts output: slice-0 blocks, 4 trajs each
    if (sl == 0) {
        const int tr = tid >> 7;
        const float* tb = ts + (size_t)((g << 2) + tr) * NTP;
        float* dts_out = out + OUT_DTS + (size_t)((g << 2) + tr) * NSTEPS;
        for (int i = tid & 127; i < NSTEPS; i += 128)
            dts_out[i] = tb[i + 1] - tb[i];
    }
    // zero fp32 state
    {
        const int tr = tid >> 7, c2 = (tid & 127) << 1;
        s_yf[tr * 256 + c2] = 0.f;  s_yf[tr * 256 + c2 + 1] = 0.f;
        s_ytf[tr * 256 + c2] = 0.f; s_ytf[tr * 256 + c2 + 1] = 0.f;
    }

    for (int it = 0; it < 512; ++it) {           // it = t+1; t = it-1
        const int t = it - 1;

        // ---- stage x (data[:, it, :]) + mask; dk1 GEMV (it>0) ----
        {
            const int tr = tid >> 7, i2 = (tid & 127) << 1;
            const float2 xv = *(const float2*)(data +
                ((size_t)((g << 2) + tr) * NTP + it) * 256 + i2);
            if (i2 < 128) {
                const unsigned px = pack2(xv.x, xv.y);
                s_in_h[tr * 192 + 128 + (i2 >> 1)] = px;
                s_ns_h[tr * 192 + 128 + (i2 >> 1)] = px;
            } else {
                float mv = wred(xv.x + xv.y);
                if (lane == 0) s_mask[tr] = mv;
            }
        }
        if (it > 0)
            gemv256<16>(DK1, s_y_h, s_y_h + 128, s_y_h + 256, s_y_h + 384,
                        s_part, w, lane, sl);
        __syncthreads();                                           // BA
        if (it > 0 && tid < 256) {   // dk reduce: wave == traj
            const int tr = tid >> 6, col = tid & 63, bi = (sl << 6) + col;
            float v = dk_b1[bi];
            #pragma unroll
            for (int i = 0; i < 8; ++i) v += s_part[tr * 512 + (i << 6) + col];
            v = fmaxf(v, 0.f) * dk_w2[bi];
            v = wred(v);
            if (lane == 0) dkp_g[sl * 4 + tr] = v;
        }
        gsync(ctrs + 0 * 16, 4u * it + 4u);                        // SYNC0
        // ---- decay, ydec, vol (all 512 threads; 2 cols each) ----
        {
            const int tr = tid >> 7, c2 = (tid & 127) << 1;
            float decay = 0.f, dt = 0.f;
            if (it > 0) {
                float dsum = dk_b2[0];
                #pragma unroll
                for (int ss = 0; ss < 4; ++ss) dsum += dkp_g[ss * 4 + tr];
                decay = fmaxf(dsum, 0.f);
                const float* tb = ts + (size_t)((g << 2) + tr) * NTP;
                dt = tb[it] - tb[it - 1];
            }
            const float e  = __expf(-decay * dt);
            const float eh = __expf(-0.5f * decay * dt);
            const float y0 = s_yf[tr * 256 + c2],  y1 = s_yf[tr * 256 + c2 + 1];
            const float z0 = s_ytf[tr * 256 + c2], z1 = s_ytf[tr * 256 + c2 + 1];
            const float yd0 = z0 + (y0 - z0) * e,  yd1 = z1 + (y1 - z1) * e;
            const float vl0 = 0.5f * (y0 + z0 + (y0 - z0) * eh);
            const float vl1 = 0.5f * (y1 + z1 + (y1 - z1) * eh);
            s_ydecf[tr * 256 + c2] = yd0; s_ydecf[tr * 256 + c2 + 1] = yd1;
            s_in_h[tr * 192 + (c2 >> 1)] = pack2(yd0, yd1);
            s_v_h[tr * 128 + (c2 >> 1)] = pack2(vl0, vl1);
        }
        __syncthreads();                                           // BB
        // ---- G1: ug1/ugt1/rg1 (K=384) + dec (K=256, it>0) ----
        gemv256<24>(UG1,  s_in_h, s_in_h + 192, s_in_h + 384, s_in_h + 576,
                    s_part, w, lane, sl);
        gemv256<24>(UGT1, s_in_h, s_in_h + 192, s_in_h + 384, s_in_h + 576,
                    s_part + 2048, w, lane, sl);
        gemv256<24>(RG1,  s_in_h, s_in_h + 192, s_in_h + 384, s_in_h + 576,
                    s_part + 4096, w, lane, sl);
        if (it > 0)
            gemv128d(DECW, s_v_h, s_v_h + 128, s_v_h + 256, s_v_h + 384,
                     s_partd, w, lane, sl);
        __syncthreads();                                           // BC
        {   // G1 reduce: 12 (mat,traj) pairs; + vol reduce/write
            const int col = tid & 63, bi = (sl << 6) + col;
            {
                const int p = tid >> 6, mat = p >> 2, tr = p & 3;
                const float* pb = s_part + mat * 2048 + tr * 512 + col;
                float v = 0.f;
                #pragma unroll
                for (int i = 0; i < 8; ++i) v += pb[i << 6];
                const float bb = (mat == 0) ? ug_b1[bi] : ((mat == 1) ? ugt_b1[bi] : rg_b1[bi]);
                v = fast_tanh(v + bb);
                const unsigned pk = packpair(v);
                if (!(col & 1)) g1h_g[p * 128 + (sl << 5) + (col >> 1)] = pk;
            }
            if (tid < 256) {
                const int tr = tid >> 6;
                const float* pb = s_part + 4096 + tr * 512 + col;
                float v = 0.f;
                #pragma unroll
                for (int i = 0; i < 8; ++i) v += pb[i << 6];
                v = fast_tanh(v + rg_b1[bi]);
                const unsigned pk = packpair(v);
                if (!(col & 1)) g1h_g[(8 + tr) * 128 + (sl << 5) + (col >> 1)] = pk;
            }
            if (it > 0 && tid < 128) {
                const int tr = tid >> 5, cc = tid & 31;
                float v = dec_b[(sl << 5) + cc];
                #pragma unroll
                for (int i = 0; i < 8; ++i) v += s_partd[tr * 256 + (i << 5) + cc];
                out[OUT_VOL + ((size_t)((g << 2) + tr) * NSTEPS + t) * DEC_OUT
                    + (sl << 5) + cc] = v;
            }
        }
        gsync(ctrs + 1 * 16, 4u * it + 4u);                        // SYNC1
        {   // copy gathered gate-h into LDS
            s_g1h[tid]        = g1h_g[tid];
            s_g1h[tid + 512]  = g1h_g[tid + 512];
            s_g1h[tid + 1024] = g1h_g[tid + 1024];
        }
        __syncthreads();                                           // BD
        // ---- G2: ug2/ugt2/rg2 (K=256) ----
        gemv256<16>(UG2,  s_g1h,        s_g1h + 128,  s_g1h + 256,  s_g1h + 384,
                    s_part, w, lane, sl);
        gemv256<16>(UGT2, s_g1h + 512,  s_g1h + 640,  s_g1h + 768,  s_g1h + 896,
                    s_part + 2048, w, lane, sl);
        gemv256<16>(RG2,  s_g1h + 1024, s_g1h + 1152, s_g1h + 1280, s_g1h + 1408,
                    s_part + 4096, w, lane, sl);
        __syncthreads();                                           // BE
        {   // G2 reduce: u,ut local; r exchanged
            const int col = tid & 63, bi = (sl << 6) + col;
            {
                const int p = tid >> 6, mat = p >> 2, tr = p & 3;
                const float* pb = s_part + mat * 2048 + tr * 512 + col;
                float v = 0.f;
                #pragma unroll
                for (int i = 0; i < 8; ++i) v += pb[i << 6];
                v = fast_sigmoid(v + (mat ? ugt_b2[bi] : ug_b2[bi]));
                if (mat == 0) s_u[tr * 64 + col] = v; else s_ut[tr * 64 + col] = v;
            }
            if (tid < 256) {
                const int tr = tid >> 6;
                const float* pb = s_part + 4096 + tr * 512 + col;
                float v = 0.f;
                #pragma unroll
                for (int i = 0; i < 8; ++i) v += pb[i << 6];
                v = fast_sigmoid(v + rg_b2[bi]);
                const unsigned pk = packpair(v);
                if (!(col & 1)) rbuf_g[tr * 128 + (sl << 5) + (col >> 1)] = pk;
            }
        }
        gsync(ctrs + 2 * 16, 4u * it + 4u);                        // SYNC2
        {   // ns input: ydec * r (full r from exchange), xh already staged
            const int tr = tid >> 7, cp = tid & 127;
            U32H2 rv; rv.u = rbuf_g[tr * 128 + cp];
            const float y0 = s_ydecf[tr * 256 + (cp << 1)];
            const float y1 = s_ydecf[tr * 256 + (cp << 1) + 1];
            s_ns_h[tr * 192 + cp] = pack2(y0 * (float)rv.h.x, y1 * (float)rv.h.y);
        }
        __syncthreads();                                           // BF
        gemv256<24>(NS1, s_ns_h, s_ns_h + 192, s_ns_h + 384, s_ns_h + 576,
                    s_part, w, lane, sl);
        __syncthreads();                                           // BG
        if (tid < 256) {
            const int tr = tid >> 6, col = tid & 63, bi = (sl << 6) + col;
            float v = ns_b1[bi];
            #pragma unroll
            for (int i = 0; i < 8; ++i) v += s_part[tr * 512 + (i << 6) + col];
            v = fast_tanh(v);
            const unsigned pk = packpair(v);
            if (!(col & 1)) nsb_g[tr * 128 + (sl << 5) + (col >> 1)] = pk;
        }
        gsync(ctrs + 3 * 16, 4u * it + 4u);                        // SYNC3
        s_nsh[tid] = nsb_g[tid];
        __syncthreads();                                           // BH
        gemv256<16>(NS2, s_nsh, s_nsh + 128, s_nsh + 256, s_nsh + 384,
                    s_part, w, lane, sl);
        __syncthreads();                                           // BI
        if (tid < 256) {   // state update for this block's 64-col slice
            const int tr = tid >> 6, col = tid & 63, bi = (sl << 6) + col;
            float nsv = ns_b2[bi];
            #pragma unroll
            for (int i = 0; i < 8; ++i) nsv += s_part[tr * 512 + (i << 6) + col];
            const float u  = s_u[tr * 64 + col];
            const float ut = s_ut[tr * 64 + col];
            const float yd = s_ydecf[tr * 256 + bi];
            const float zt = s_ytf[tr * 256 + bi];
            const bool mk = s_mask[tr] > 0.f;
            const float ny  = (1.f - u) * nsv + u * yd;
            const float nyt = (1.f - ut) * nsv + ut * zt;
            ybuf_g[tr * 256 + bi] = mk ? ny : yd;
            ytb_g[tr * 256 + bi]  = mk ? nyt : zt;
        }
        gsync(ctrs + 4 * 16, 4u * it + 4u);                        // SYNC4
        {   // refresh full fp32 state + packed y
            const int tr = tid >> 7, c2 = (tid & 127) << 1;
            const float2 ny = *(const float2*)(ybuf_g + tr * 256 + c2);
            const float2 nt = *(const float2*)(ytb_g + tr * 256 + c2);
            s_yf[tr * 256 + c2] = ny.x;  s_yf[tr * 256 + c2 + 1] = ny.y;
            s_ytf[tr * 256 + c2] = nt.x; s_ytf[tr * 256 + c2 + 1] = nt.y;
            s_y_h[tr * 128 + (c2 >> 1)] = pack2(ny.x, ny.y);
        }
        __syncthreads();                                           // BJ
    }

    // prev_y: slice-0 blocks write final y
    if (sl == 0) {
        const int tr = tid >> 7, c2 = (tid & 127) << 1;
        out[(size_t)((g << 2) + tr) * 256 + c2]     = s_yf[tr * 256 + c2];
        out[(size_t)((g << 2) + tr) * 256 + c2 + 1] = s_yf[tr * 256 + c2 + 1];
    }
}

extern "C" void kernel_launch(void* const* d_in, const int* in_sizes, int n_in,
                              void* d_out, int out_size, void* d_ws, size_t ws_size,
                              hipStream_t stream) {
    const float* data   = (const float*)d_in[0];
    const float* ts     = (const float*)d_in[1];
    const float* ug_w1  = (const float*)d_in[2];
    const float* ug_b1  = (const float*)d_in[3];
    const float* ug_w2  = (const float*)d_in[4];
    const float* ug_b2  = (const float*)d_in[5];
    const float* ugt_w1 = (const float*)d_in[6];
    const float* ugt_b1 = (const float*)d_in[7];
    const float* ugt_w2 = (const float*)d_in[8];
    const float* ugt_b2 = (const float*)d_in[9];
    const float* rg_w1  = (const float*)d_in[10];
    const float* rg_b1  = (const float*)d_in[11];
    const float* rg_w2  = (const float*)d_in[12];
    const float* rg_b2  = (const float*)d_in[13];
    // d_in[14..17] = rgt_* : unused by the reference
    const float* ns_w1  = (const float*)d_in[18];
    const float* ns_b1  = (const float*)d_in[19];
    const float* ns_w2  = (const float*)d_in[20];
    const float* ns_b2  = (const float*)d_in[21];
    const float* dk_w1  = (const float*)d_in[22];
    const float* dk_b1  = (const float*)d_in[23];
    const float* dk_w2  = (const float*)d_in[24];
    const float* dk_b2  = (const float*)d_in[25];
    const float* dec_w  = (const float*)d_in[26];
    const float* dec_b  = (const float*)d_in[27];

    char* wsb = (char*)d_ws;

    init_ctrs<<<1, 512, 0, stream>>>((unsigned int*)(wsb + WS_CTR));
    convert_w<<<WU_TOT / 256, 256, 0, stream>>>(ug_w1, ug_w2, ugt_w1, ugt_w2,
                                                rg_w1, rg_w2, ns_w1, ns_w2,
                                                dk_w1, dec_w, (unsigned int*)wsb);

    rnn_decay_kernel4<<<256, 512, 0, stream>>>(
        data, ts, ug_b1, ug_b2, ugt_b1, ugt_b2, rg_b1, rg_b2, ns_b1, ns_b2,
        dk_b1, dk_w2, dk_b2, dec_b, wsb, (float*)d_out);
}